// Round 9
// baseline (87.657 us; speedup 1.0000x reference)
//
#include <hip/hip_runtime.h>
#include <cstdint>
#include <cstddef>

#define N_TOK  16384
#define NEXP   64
#define KDIM   2048
#define CAP    256   // ceil(16384/64 * 1.0) = 256
#define NE_TOT ((size_t)N_TOK * NEXP)

typedef __attribute__((ext_vector_type(8))) short short8;
typedef __attribute__((ext_vector_type(4))) float f32x4;
typedef __attribute__((ext_vector_type(4))) unsigned int uint4x;

__device__ __forceinline__ unsigned short bf16_rtn(float f) {
  unsigned u = __float_as_uint(f);
  u += 0x7FFFu + ((u >> 16) & 1u);
  return (unsigned short)(u >> 16);
}
__device__ __forceinline__ float bf16_f(unsigned short h) {
  return __uint_as_float((unsigned)h << 16);
}
__device__ __forceinline__ f32x4 MF(short8 a, short8 b, f32x4 c) {
  return __builtin_amdgcn_mfma_f32_16x16x32_bf16(a, b, c, 0, 0, 0);
}
// HW packed f32->bf16 RTNE (bit-identical to bf16_rtn; verified R7/R8)
__device__ __forceinline__ unsigned cvt_pk(float a, float b) {
  unsigned r;
  asm("v_cvt_pk_bf16_f32 %0, %1, %2" : "=v"(r) : "v"(a), "v"(b));
  return r;
}
__device__ __forceinline__ float lo16f(unsigned u) {
  return __uint_as_float(u << 16);
}
__device__ __forceinline__ float hi16f(unsigned u) {
  return __uint_as_float(u & 0xFFFF0000u);
}

// ---------------------------------------------------------------------------
// Kernel 0: split W into 3 bf16 digits, packed [k/8][col][8] (unchanged).
// ---------------------------------------------------------------------------
__global__ __launch_bounds__(256) void wdigits(const float* __restrict__ W,
    unsigned short* __restrict__ Wh, unsigned short* __restrict__ Wl,
    unsigned short* __restrict__ Wq) {
  const int e = (int)blockIdx.x * 256 + (int)threadIdx.x;  // 0..131071
  const int col = e >> 11;
  const int k   = e & 2047;
  const float w = W[(size_t)col * KDIM + k];
  const unsigned short h = bf16_rtn(w);
  const float r1 = w - bf16_f(h);
  const unsigned short lo = bf16_rtn(r1);
  const float r2 = r1 - bf16_f(lo);
  const unsigned short q = bf16_rtn(r2);
  const size_t idx = (size_t)(k >> 3) * 512 + (size_t)col * 8 + (k & 7);
  Wh[idx] = h; Wl[idx] = lo; Wq[idx] = q;
}

// ---------------------------------------------------------------------------
// Kernel 1: logits via 6-term split-bf16 MFMA.
//   A staged through per-wave double-buffered LDS (2x2KB/wave) with
//   global_load_lds (coalesced full-line loads; XOR-swizzled source +
//   XOR-swizzled ds_read -> 2-way banks = free). No barriers: each wave
//   stages only its own 16 rows; prev-stage completion via counted
//   s_waitcnt vmcnt(2). All 12 B-fragments (L2-hot) loaded upfront per
//   step (MLP=12). MFMA order: 6 rounds x 4 independent accs (breaks the
//   dependent-accumulate chain). Per-acc MFMA order unchanged from R7/R8
//   -> logits bit-identical.
// ---------------------------------------------------------------------------
__device__ __forceinline__ void cvt8pk(float4 a, float4 b,
                                       short8& h, short8& lo, short8& q) {
  const float f0 = a.x, f1 = a.y, f2 = a.z, f3 = a.w;
  const float f4 = b.x, f5 = b.y, f6 = b.z, f7 = b.w;
  const unsigned h0 = cvt_pk(f0, f1), h1 = cvt_pk(f2, f3);
  const unsigned h2 = cvt_pk(f4, f5), h3 = cvt_pk(f6, f7);
  const float r0 = f0 - lo16f(h0), r1 = f1 - hi16f(h0);
  const float r2 = f2 - lo16f(h1), r3 = f3 - hi16f(h1);
  const float r4 = f4 - lo16f(h2), r5 = f5 - hi16f(h2);
  const float r6 = f6 - lo16f(h3), r7 = f7 - hi16f(h3);
  const unsigned l0 = cvt_pk(r0, r1), l1 = cvt_pk(r2, r3);
  const unsigned l2 = cvt_pk(r4, r5), l3 = cvt_pk(r6, r7);
  const float s0 = r0 - lo16f(l0), s1 = r1 - hi16f(l0);
  const float s2 = r2 - lo16f(l1), s3 = r3 - hi16f(l1);
  const float s4 = r4 - lo16f(l2), s5 = r5 - hi16f(l2);
  const float s6 = r6 - lo16f(l3), s7 = r7 - hi16f(l3);
  const unsigned q0 = cvt_pk(s0, s1), q1 = cvt_pk(s2, s3);
  const unsigned q2 = cvt_pk(s4, s5), q3 = cvt_pk(s6, s7);
  h  = __builtin_bit_cast(short8, (uint4x){h0, h1, h2, h3});
  lo = __builtin_bit_cast(short8, (uint4x){l0, l1, l2, l3});
  q  = __builtin_bit_cast(short8, (uint4x){q0, q1, q2, q3});
}

template <int KS>
__global__ __launch_bounds__(256) void gemm_mfma(const float* __restrict__ x,
    const unsigned short* __restrict__ Wh, const unsigned short* __restrict__ Wl,
    const unsigned short* __restrict__ Wq, float* __restrict__ part) {
  constexpr int NSTEP = (KDIM / KS) / 32;
  __shared__ float xs[4][2][512];   // [wave][buf][16 rows x 32 k] 16 KB
  const int tid = (int)threadIdx.x;
  const int l   = tid & 63;
  const int wid = tid >> 6;
  const int ks  = (int)blockIdx.x >> 8;   // 256 blocks per k-slice
  const int mt  = (int)blockIdx.x & 255;  // 64-row block tiles
  const int row0 = mt * 64 + wid * 16;    // this wave's 16 rows
  const int kBeg = ks * (KDIM / KS);
  const int lr = l & 15;
  const int lk = l >> 4;

  // --- staging addresses (global source is per-lane, XOR-pre-swizzled) ---
  const int srow = l >> 3;                 // 0..7 (f=0); f=1 adds 8 rows
  const int scol = ((l & 7) * 4) ^ ((srow & 7) << 2);  // swizzled col (floats)
  const float* sp0 = x + (size_t)(row0 + srow)     * KDIM + kBeg + scol;
  const float* sp1 = x + (size_t)(row0 + 8 + srow) * KDIM + kBeg + scol;

  // --- ds_read addresses (same XOR swizzle) ---
  const int rsw = (lr & 7) << 2;
  const float* rp0 = &xs[wid][0][lr * 32 + ((lk * 8)     ^ rsw)];
  const float* rp1 = &xs[wid][0][lr * 32 + ((lk * 8 + 4) ^ rsw)];

  // --- B fragment base ---
  const size_t bbase = ((size_t)((kBeg >> 3) + lk)) * 64 + lr;
  const short8* BH = (const short8*)Wh + bbase;
  const short8* BL = (const short8*)Wl + bbase;
  const short8* BQ = (const short8*)Wq + bbase;

  f32x4 acc0 = {0.f,0.f,0.f,0.f}, acc1 = {0.f,0.f,0.f,0.f};
  f32x4 acc2 = {0.f,0.f,0.f,0.f}, acc3 = {0.f,0.f,0.f,0.f};

#define STAGE(buf, koff)                                                     \
  __builtin_amdgcn_global_load_lds((const float*)(sp0 + (koff)),             \
                                   &xs[wid][(buf)][0],   16, 0, 0);          \
  __builtin_amdgcn_global_load_lds((const float*)(sp1 + (koff)),             \
                                   &xs[wid][(buf)][256], 16, 0, 0);

  STAGE(0, 0)  // prologue

  for (int s = 0; s < NSTEP; ++s) {
    const int cur = s & 1;
    // stage next step into the other buffer (dummy re-stage of k=0 on last)
    const int nk = (s + 1 < NSTEP) ? (s + 1) * 32 : 0;
    if (cur == 0) { STAGE(1, nk) } else { STAGE(0, nk) }
    // wait for PREVIOUS stage (2 newest loads may stay in flight)
    asm volatile("s_waitcnt vmcnt(2)" ::: "memory");

    // A fragments from own LDS slice
    float4 A0 = *(const float4*)(rp0 + cur * 512);
    float4 A1 = *(const float4*)(rp1 + cur * 512);

    short8 a_h, a_l, a_q;
    cvt8pk(A0, A1, a_h, a_l, a_q);

    // all 12 B fragments upfront (L2-hot, MLP)
    const int so = s * 256;
    short8 bh0 = BH[so +  0], bh1 = BH[so + 16], bh2 = BH[so + 32], bh3 = BH[so + 48];
    short8 bl0 = BL[so +  0], bl1 = BL[so + 16], bl2 = BL[so + 32], bl3 = BL[so + 48];
    short8 bq0 = BQ[so +  0], bq1 = BQ[so + 16], bq2 = BQ[so + 32], bq3 = BQ[so + 48];

    // 6 rounds x 4 independent accs (same per-acc order as R7/R8)
    acc0 = MF(a_h, bh0, acc0); acc1 = MF(a_h, bh1, acc1);
    acc2 = MF(a_h, bh2, acc2); acc3 = MF(a_h, bh3, acc3);
    acc0 = MF(a_h, bl0, acc0); acc1 = MF(a_h, bl1, acc1);
    acc2 = MF(a_h, bl2, acc2); acc3 = MF(a_h, bl3, acc3);
    acc0 = MF(a_l, bh0, acc0); acc1 = MF(a_l, bh1, acc1);
    acc2 = MF(a_l, bh2, acc2); acc3 = MF(a_l, bh3, acc3);
    acc0 = MF(a_l, bl0, acc0); acc1 = MF(a_l, bl1, acc1);
    acc2 = MF(a_l, bl2, acc2); acc3 = MF(a_l, bl3, acc3);
    acc0 = MF(a_q, bh0, acc0); acc1 = MF(a_q, bh1, acc1);
    acc2 = MF(a_q, bh2, acc2); acc3 = MF(a_q, bh3, acc3);
    acc0 = MF(a_h, bq0, acc0); acc1 = MF(a_h, bq1, acc1);
    acc2 = MF(a_h, bq2, acc2); acc3 = MF(a_h, bq3, acc3);
  }
#undef STAGE

  float* pout = part + (size_t)ks * NE_TOT;
  const int rb = row0 + lk * 4;
#pragma unroll
  for (int r = 0; r < 4; ++r) {
    pout[(size_t)(rb + r) * 64 +  0 + lr] = acc0[r];
    pout[(size_t)(rb + r) * 64 + 16 + lr] = acc1[r];
    pout[(size_t)(rb + r) * 64 + 32 + lr] = acc2[r];
    pout[(size_t)(rb + r) * 64 + 48 + lr] = acc3[r];
  }
}

// ---------------------------------------------------------------------------
// Kernel 2: per-row gating -> TRANSPOSED outputs (unchanged — verified)
// ---------------------------------------------------------------------------
template <int KS>
__global__ __launch_bounds__(1024) void gate_rows(const float* __restrict__ part,
                                                  float* __restrict__ gatesT,
                                                  float* __restrict__ tamT) {
  __shared__ float gt[64][65];
  __shared__ float tt[64][65];
  const int tid  = (int)threadIdx.x;
  const int lane = tid & 63;
  const int wid  = tid >> 6;
  const int row0 = (int)blockIdx.x * 64;

#pragma unroll
  for (int r = 0; r < 4; ++r) {
    const int rloc = wid * 4 + r;
    const size_t base = (size_t)(row0 + rloc) * NEXP;

    float logit = 0.f;
#pragma unroll
    for (int s = 0; s < KS; ++s)
      logit += part[(size_t)s * NE_TOT + base + lane];

    float m = logit;
#pragma unroll
    for (int off = 32; off > 0; off >>= 1) m = fmaxf(m, __shfl_xor(m, off));
    float p = expf(logit - m);
    float sum = p;
#pragma unroll
    for (int off = 32; off > 0; off >>= 1) sum += __shfl_xor(sum, off);
    const float gate = p / sum;

    float g = gate;
    int idx = lane;
#pragma unroll
    for (int k = 2; k <= 64; k <<= 1) {
#pragma unroll
      for (int j = k >> 1; j > 0; j >>= 1) {
        float og = __shfl_xor(g, j);
        int   oi = __shfl_xor(idx, j);
        bool iLower     = (lane & j) == 0;
        bool wantFirst  = ((lane & k) == 0) ? iLower : !iLower;
        bool otherFirst = (og > g) || (og == g && oi < idx);
        if (otherFirst == wantFirst) { g = og; idx = oi; }
      }
    }

    float cum = g;
#pragma unroll
    for (int off = 1; off < 64; off <<= 1) {
      float t = __shfl_up(cum, off);
      if (lane >= off) cum += t;
    }
    const bool chosen = (lane == 0) || ((cum - g) < 0.5f);
    const float imp = chosen ? ((float)(NEXP - lane) + g) : 0.f;

    gt[rloc][lane] = gate;
    tt[rloc][idx]  = imp;
  }
  __syncthreads();

#pragma unroll
  for (int p = 0; p < 4; ++p) {
    const int e = p * 16 + wid;
    gatesT[(size_t)e * N_TOK + row0 + lane] = gt[lane][e];
    tamT  [(size_t)e * N_TOK + row0 + lane] = tt[lane][e];
  }
}

// ---------------------------------------------------------------------------
// Kernel 3: per-expert capacity truncation (unchanged — verified)
// ---------------------------------------------------------------------------
__global__ __launch_bounds__(1024) void expert_select(
    const float* __restrict__ gatesT, const float* __restrict__ tamT,
    float* __restrict__ me_sum, int* __restrict__ ce_cnt,
    float* __restrict__ combT) {
  __shared__ int   hist16[16][256];
  __shared__ int   hist[256];
  __shared__ float wsum[16];
  __shared__ int   wice[16];
  __shared__ int   wnnz[16];
  __shared__ int   wcnt[16];
  __shared__ unsigned sh_prefix;
  __shared__ int      sh_k;
  __shared__ int      sh_nnz;

  const int e    = (int)blockIdx.x;
  const int tid  = (int)threadIdx.x;
  const int lane = tid & 63;
  const int wid  = tid >> 6;
  const float* tcol = tamT   + (size_t)e * N_TOK;
  const float* gcol = gatesT + (size_t)e * N_TOK;

  float gsum = 0.f;
  int ccnt = 0, nnzl = 0;
#pragma unroll
  for (int k = 0; k < 4; ++k) {
    int i4 = tid + k * 1024;
    float4 tv = reinterpret_cast<const float4*>(tcol)[i4];
    float4 gv = reinterpret_cast<const float4*>(gcol)[i4];
    gsum += gv.x + gv.y + gv.z + gv.w;
    ccnt += (tv.x > 64.f) + (tv.y > 64.f) + (tv.z > 64.f) + (tv.w > 64.f);
    nnzl += (tv.x != 0.f) + (tv.y != 0.f) + (tv.z != 0.f) + (tv.w != 0.f);
  }
#pragma unroll
  for (int off = 32; off > 0; off >>= 1) {
    gsum += __shfl_xor(gsum, off);
    ccnt += __shfl_xor(ccnt, off);
    nnzl += __shfl_xor(nnzl, off);
  }
  if (lane == 0) { wsum[wid] = gsum; wice[wid] = ccnt; wnnz[wid] = nnzl; }
  __syncthreads();
  if (tid == 0) {
    float t = 0.f; int c = 0, nz = 0;
    for (int w = 0; w < 16; ++w) { t += wsum[w]; c += wice[w]; nz += wnnz[w]; }
    me_sum[e] = t; ce_cnt[e] = c; sh_nnz = nz;
  }
  __syncthreads();
  const int nnz = sh_nnz;

  unsigned vstar = 0u;
  int meq = 0;
  if (nnz > CAP) {
    unsigned prefix = 0;
    int krem = CAP;
    for (int round = 0; round < 4; ++round) {
      const int shift = 24 - 8 * round;
      const unsigned maskAbove =
          (round == 0) ? 0u : (0xFFFFFFFFu << (shift + 8));
      for (int z = tid; z < 16 * 256; z += 1024) ((int*)hist16)[z] = 0;
      __syncthreads();
#pragma unroll
      for (int k = 0; k < 16; ++k) {
        unsigned u = __float_as_uint(tcol[tid + k * 1024]);
        if (u != 0u && (u & maskAbove) == prefix)
          atomicAdd(&hist16[wid][(u >> shift) & 255], 1);
      }
      __syncthreads();
      if (tid < 256) {
        int s = 0;
#pragma unroll
        for (int w = 0; w < 16; ++w) s += hist16[w][tid];
        hist[tid] = s;
      }
      __syncthreads();
      if (wid == 0) {
        int h0 = hist[lane * 4 + 0], h1 = hist[lane * 4 + 1];
        int h2 = hist[lane * 4 + 2], h3 = hist[lane * 4 + 3];
        int lsum = h0 + h1 + h2 + h3;
        int suf = lsum;
#pragma unroll
        for (int off = 1; off < 64; off <<= 1) {
          int t = __shfl_down(suf, off);
          if (lane + off < 64) suf += t;
        }
        int above = suf - lsum;
        int S3 = above + h3, S2 = S3 + h2, S1 = S2 + h1, S0 = S1 + h0;
        if (S0 >= krem && S1    < krem) { sh_prefix = prefix | ((unsigned)(lane*4+0) << shift); sh_k = krem - S1;    }
        if (S1 >= krem && S2    < krem) { sh_prefix = prefix | ((unsigned)(lane*4+1) << shift); sh_k = krem - S2;    }
        if (S2 >= krem && S3    < krem) { sh_prefix = prefix | ((unsigned)(lane*4+2) << shift); sh_k = krem - S3;    }
        if (S3 >= krem && above < krem) { sh_prefix = prefix | ((unsigned)(lane*4+3) << shift); sh_k = krem - above; }
      }
      __syncthreads();
      prefix = sh_prefix;
      krem   = sh_k;
      __syncthreads();
    }
    vstar = prefix;
    meq   = krem;
  }

  float4 tq[4];
#pragma unroll
  for (int q = 0; q < 4; ++q)
    tq[q] = reinterpret_cast<const float4*>(tcol)[tid * 4 + q];
  int cnt = 0;
#pragma unroll
  for (int q = 0; q < 4; ++q) {
    cnt += (__float_as_uint(tq[q].x) == vstar);
    cnt += (__float_as_uint(tq[q].y) == vstar);
    cnt += (__float_as_uint(tq[q].z) == vstar);
    cnt += (__float_as_uint(tq[q].w) == vstar);
  }
  int inc = cnt;
#pragma unroll
  for (int off = 1; off < 64; off <<= 1) {
    int t = __shfl_up(inc, off);
    if (lane >= off) inc += t;
  }
  if (lane == 63) wcnt[wid] = inc;
  __syncthreads();
  if (tid == 0) {
    int run = 0;
    for (int w = 0; w < 16; ++w) { int t = wcnt[w]; wcnt[w] = run; run += t; }
  }
  __syncthreads();
  int exc = (inc - cnt) + wcnt[wid];

  float* ccol = combT + (size_t)e * N_TOK;
#pragma unroll
  for (int q = 0; q < 4; ++q) {
    float4 gq = reinterpret_cast<const float4*>(gcol)[tid * 4 + q];
    float ov[4];
    const float tv[4] = {tq[q].x, tq[q].y, tq[q].z, tq[q].w};
    const float gv[4] = {gq.x, gq.y, gq.z, gq.w};
#pragma unroll
    for (int j = 0; j < 4; ++j) {
      unsigned u = __float_as_uint(tv[j]);
      bool keep;
      if (u == vstar) { keep = (exc < meq); ++exc; }
      else            { keep = (u > vstar); }
      ov[j] = (keep && u != 0u) ? gv[j] : 0.f;
    }
    reinterpret_cast<float4*>(ccol)[tid * 4 + q] =
        make_float4(ov[0], ov[1], ov[2], ov[3]);
  }
}

// ---------------------------------------------------------------------------
// Kernel 4: transpose combT[e][t] -> out[t][e]; block 0 also computes l_aux
// ---------------------------------------------------------------------------
__global__ __launch_bounds__(1024) void transpose_out(
    const float* __restrict__ combT, float* __restrict__ out1,
    const float* __restrict__ me_sum, const int* __restrict__ ce_cnt,
    float* __restrict__ out0) {
  __shared__ float tile[64][65];
  const int tid  = (int)threadIdx.x;
  const int lane = tid & 63;
  const int wid  = tid >> 6;
  const int tok0 = (int)blockIdx.x * 64;
#pragma unroll
  for (int p = 0; p < 4; ++p) {
    const int e = p * 16 + wid;
    tile[lane][e] = combT[(size_t)e * N_TOK + tok0 + lane];
  }
  __syncthreads();
#pragma unroll
  for (int q = 0; q < 4; ++q) {
    const int tok = q * 16 + wid;
    out1[(size_t)(tok0 + tok) * NEXP + lane] = tile[tok][lane];
  }
  if (blockIdx.x == 0 && wid == 0) {
    float v = (me_sum[lane] / (float)N_TOK) *
              ((float)ce_cnt[lane] / (float)N_TOK);
#pragma unroll
    for (int off = 32; off > 0; off >>= 1) v += __shfl_xor(v, off);
    if (lane == 0) out0[0] = v * (float)NEXP;
  }
}

// ---------------------------------------------------------------------------
extern "C" void kernel_launch(void* const* d_in, const int* in_sizes, int n_in,
                              void* d_out, int out_size, void* d_ws, size_t ws_size,
                              hipStream_t stream) {
  const float* x = (const float*)d_in[0];
  const float* W = (const float*)d_in[1];
  float* out = (float*)d_out;
  float* ws  = (float*)d_ws;

  // KS=8 needs (8+2)*4MB scratch; fall back to KS=4 if ws is smaller.
  const bool ks8 = ws_size >= (size_t)(8 + 2) * NE_TOT * 4 + 1024;

  const int KS = ks8 ? 8 : 4;
  float* part   = ws;                       // KS * 4 MB
  float* combT  = ws;                       // aliases part (dead by then)
  float* gatesT = ws + (size_t)KS * NE_TOT; // 4 MB
  float* tamT   = gatesT + NE_TOT;          // 4 MB
  float* me     = tamT + NE_TOT;
  int*   ce     = (int*)(me + 64);

  // W digit arrays (768 KB) live in the gatesT region: written by wdigits,
  // consumed by gemm_mfma, dead before gate_rows overwrites gatesT.
  unsigned short* Wh = (unsigned short*)gatesT;
  unsigned short* Wl = Wh + (size_t)NEXP * KDIM;
  unsigned short* Wq = Wl + (size_t)NEXP * KDIM;

  wdigits<<<(NEXP * KDIM) / 256, 256, 0, stream>>>(W, Wh, Wl, Wq);
  if (ks8) gemm_mfma<8><<<256 * 8, 256, 0, stream>>>(x, Wh, Wl, Wq, part);
  else     gemm_mfma<4><<<256 * 4, 256, 0, stream>>>(x, Wh, Wl, Wq, part);
  if (ks8) gate_rows<8><<<N_TOK / 64, 1024, 0, stream>>>(part, gatesT, tamT);
  else     gate_rows<4><<<N_TOK / 64, 1024, 0, stream>>>(part, gatesT, tamT);
  expert_select<<<NEXP, 1024, 0, stream>>>(gatesT, tamT, me, ce, combT);
  transpose_out<<<N_TOK / 64, 1024, 0, stream>>>(combT, out + 1, me, ce, out);
}

// Round 10
// 87.212 us; speedup vs baseline: 1.0051x; 1.0051x over previous
//
#include <hip/hip_runtime.h>
#include <cstdint>
#include <cstddef>

#define N_TOK  16384
#define NEXP   64
#define KDIM   2048
#define CAP    256   // ceil(16384/64 * 1.0) = 256
#define NE_TOT ((size_t)N_TOK * NEXP)

typedef __attribute__((ext_vector_type(8))) short short8;
typedef __attribute__((ext_vector_type(4))) float f32x4;
typedef __attribute__((ext_vector_type(4))) unsigned int uint4x;

__device__ __forceinline__ unsigned short bf16_rtn(float f) {
  unsigned u = __float_as_uint(f);
  u += 0x7FFFu + ((u >> 16) & 1u);
  return (unsigned short)(u >> 16);
}
__device__ __forceinline__ float bf16_f(unsigned short h) {
  return __uint_as_float((unsigned)h << 16);
}
__device__ __forceinline__ f32x4 MF(short8 a, short8 b, f32x4 c) {
  return __builtin_amdgcn_mfma_f32_16x16x32_bf16(a, b, c, 0, 0, 0);
}
// HW packed f32->bf16 RTNE (bit-identical to bf16_rtn; verified R6->R7)
__device__ __forceinline__ unsigned cvt_pk(float a, float b) {
  unsigned r;
  asm("v_cvt_pk_bf16_f32 %0, %1, %2" : "=v"(r) : "v"(a), "v"(b));
  return r;
}
__device__ __forceinline__ float lo16f(unsigned u) {
  return __uint_as_float(u << 16);
}
__device__ __forceinline__ float hi16f(unsigned u) {
  return __uint_as_float(u & 0xFFFF0000u);
}

// ---------------------------------------------------------------------------
// Kernel 0: split W into 3 bf16 digits, packed [k/8][col][8] (unchanged).
// ---------------------------------------------------------------------------
__global__ __launch_bounds__(256) void wdigits(const float* __restrict__ W,
    unsigned short* __restrict__ Wh, unsigned short* __restrict__ Wl,
    unsigned short* __restrict__ Wq) {
  const int e = (int)blockIdx.x * 256 + (int)threadIdx.x;  // 0..131071
  const int col = e >> 11;
  const int k   = e & 2047;
  const float w = W[(size_t)col * KDIM + k];
  const unsigned short h = bf16_rtn(w);
  const float r1 = w - bf16_f(h);
  const unsigned short lo = bf16_rtn(r1);
  const float r2 = r1 - bf16_f(lo);
  const unsigned short q = bf16_rtn(r2);
  const size_t idx = (size_t)(k >> 3) * 512 + (size_t)col * 8 + (k & 7);
  Wh[idx] = h; Wl[idx] = lo; Wq[idx] = q;
}

// ---------------------------------------------------------------------------
// Kernel 1: logits via 6-term split-bf16 MFMA.
//   KEY CHANGE vs R8/R9: __launch_bounds__(256, 2) raises the VGPR cap to
//   ~256 so ALL 12 B-fragments of a step stay register-resident, plus a
//   hand-written even/odd double-buffer: next step's 12 B-frags + A are
//   issued BEFORE this step's 24-MFMA block (~466 cyc) -> L2 latency fully
//   hidden. ~160 VGPR -> 3 waves/SIMD (MFMA demand is residency-independent
//   once loads are in flight). Per-acc MFMA order unchanged -> bit-identical.
// ---------------------------------------------------------------------------
__device__ __forceinline__ void cvt8pk(float4 a, float4 b,
                                       short8& h, short8& lo, short8& q) {
  const float f0 = a.x, f1 = a.y, f2 = a.z, f3 = a.w;
  const float f4 = b.x, f5 = b.y, f6 = b.z, f7 = b.w;
  const unsigned h0 = cvt_pk(f0, f1), h1 = cvt_pk(f2, f3);
  const unsigned h2 = cvt_pk(f4, f5), h3 = cvt_pk(f6, f7);
  const float r0 = f0 - lo16f(h0), r1 = f1 - hi16f(h0);
  const float r2 = f2 - lo16f(h1), r3 = f3 - hi16f(h1);
  const float r4 = f4 - lo16f(h2), r5 = f5 - hi16f(h2);
  const float r6 = f6 - lo16f(h3), r7 = f7 - hi16f(h3);
  const unsigned l0 = cvt_pk(r0, r1), l1 = cvt_pk(r2, r3);
  const unsigned l2 = cvt_pk(r4, r5), l3 = cvt_pk(r6, r7);
  const float s0 = r0 - lo16f(l0), s1 = r1 - hi16f(l0);
  const float s2 = r2 - lo16f(l1), s3 = r3 - hi16f(l1);
  const float s4 = r4 - lo16f(l2), s5 = r5 - hi16f(l2);
  const float s6 = r6 - lo16f(l3), s7 = r7 - hi16f(l3);
  const unsigned q0 = cvt_pk(s0, s1), q1 = cvt_pk(s2, s3);
  const unsigned q2 = cvt_pk(s4, s5), q3 = cvt_pk(s6, s7);
  h  = __builtin_bit_cast(short8, (uint4x){h0, h1, h2, h3});
  lo = __builtin_bit_cast(short8, (uint4x){l0, l1, l2, l3});
  q  = __builtin_bit_cast(short8, (uint4x){q0, q1, q2, q3});
}

template <int KS>
__global__ __launch_bounds__(256, 2) void gemm_mfma(const float* __restrict__ x,
    const unsigned short* __restrict__ Wh, const unsigned short* __restrict__ Wl,
    const unsigned short* __restrict__ Wq, float* __restrict__ part) {
  constexpr int NSTEP = (KDIM / KS) / 32;   // 8 for KS=8 (even)
  const int tid = (int)threadIdx.x;
  const int l   = tid & 63;
  const int wv  = tid >> 6;
  const int ks  = (int)blockIdx.x >> 8;                 // 256 blocks per slice
  const int mt  = (((int)blockIdx.x & 255) << 2) + wv;  // 0..1023
  const int row0 = mt * 16;
  const int kBeg = ks * (KDIM / KS);
  const int lr = l & 15;
  const int lk = l >> 4;

  f32x4 acc0 = {0.f,0.f,0.f,0.f}, acc1 = {0.f,0.f,0.f,0.f};
  f32x4 acc2 = {0.f,0.f,0.f,0.f}, acc3 = {0.f,0.f,0.f,0.f};

  const float* pa = x + (size_t)(row0 + lr) * KDIM + kBeg + lk * 8;
  const size_t bbase = ((size_t)((kBeg >> 3) + lk)) * 64 + lr;
  const short8* BH = (const short8*)Wh + bbase;
  const short8* BL = (const short8*)Wl + bbase;
  const short8* BQ = (const short8*)Wq + bbase;

  // ---- prologue: A[0] and even-set B[step 0] ----
  float4 A0 = *(const float4*)pa;
  float4 A1 = *(const float4*)(pa + 4);
  short8 eh0 = BH[ 0], eh1 = BH[16], eh2 = BH[32], eh3 = BH[48];
  short8 el0 = BL[ 0], el1 = BL[16], el2 = BL[32], el3 = BL[48];
  short8 eq0 = BQ[ 0], eq1 = BQ[16], eq2 = BQ[32], eq3 = BQ[48];

#define MFMA24(BH0,BH1,BH2,BH3, BL0,BL1,BL2,BL3, BQ0,BQ1,BQ2,BQ3)    \
    acc0 = MF(a_h, BH0, acc0); acc1 = MF(a_h, BH1, acc1);            \
    acc2 = MF(a_h, BH2, acc2); acc3 = MF(a_h, BH3, acc3);            \
    acc0 = MF(a_h, BL0, acc0); acc1 = MF(a_h, BL1, acc1);            \
    acc2 = MF(a_h, BL2, acc2); acc3 = MF(a_h, BL3, acc3);            \
    acc0 = MF(a_l, BH0, acc0); acc1 = MF(a_l, BH1, acc1);            \
    acc2 = MF(a_l, BH2, acc2); acc3 = MF(a_l, BH3, acc3);            \
    acc0 = MF(a_l, BL0, acc0); acc1 = MF(a_l, BL1, acc1);            \
    acc2 = MF(a_l, BL2, acc2); acc3 = MF(a_l, BL3, acc3);            \
    acc0 = MF(a_q, BH0, acc0); acc1 = MF(a_q, BH1, acc1);            \
    acc2 = MF(a_q, BH2, acc2); acc3 = MF(a_q, BH3, acc3);            \
    acc0 = MF(a_h, BQ0, acc0); acc1 = MF(a_h, BQ1, acc1);            \
    acc2 = MF(a_h, BQ2, acc2); acc3 = MF(a_h, BQ3, acc3);

  for (int s2 = 0; s2 < NSTEP / 2; ++s2) {
    // ============ even step (consumes e-set, loads o-set) ============
    const int sO  = 2 * s2 + 1;
    const int soO = sO * 256;
    short8 oh0 = BH[soO +  0], oh1 = BH[soO + 16], oh2 = BH[soO + 32], oh3 = BH[soO + 48];
    short8 ol0 = BL[soO +  0], ol1 = BL[soO + 16], ol2 = BL[soO + 32], ol3 = BL[soO + 48];
    short8 oq0 = BQ[soO +  0], oq1 = BQ[soO + 16], oq2 = BQ[soO + 32], oq3 = BQ[soO + 48];
    float4 N0 = *(const float4*)(pa + sO * 32);
    float4 N1 = *(const float4*)(pa + sO * 32 + 4);
    {
      short8 a_h, a_l, a_q;
      cvt8pk(A0, A1, a_h, a_l, a_q);
      MFMA24(eh0,eh1,eh2,eh3, el0,el1,el2,el3, eq0,eq1,eq2,eq3)
    }
    // ============ odd step (consumes o-set, reloads e-set) ============
    const int sE2  = (s2 + 1 < NSTEP / 2) ? (2 * s2 + 2) : 0;  // clamp (dummy)
    const int soE2 = sE2 * 256;
    eh0 = BH[soE2 +  0]; eh1 = BH[soE2 + 16]; eh2 = BH[soE2 + 32]; eh3 = BH[soE2 + 48];
    el0 = BL[soE2 +  0]; el1 = BL[soE2 + 16]; el2 = BL[soE2 + 32]; el3 = BL[soE2 + 48];
    eq0 = BQ[soE2 +  0]; eq1 = BQ[soE2 + 16]; eq2 = BQ[soE2 + 32]; eq3 = BQ[soE2 + 48];
    float4 M0 = *(const float4*)(pa + sE2 * 32);
    float4 M1 = *(const float4*)(pa + sE2 * 32 + 4);
    {
      short8 a_h, a_l, a_q;
      cvt8pk(N0, N1, a_h, a_l, a_q);
      MFMA24(oh0,oh1,oh2,oh3, ol0,ol1,ol2,ol3, oq0,oq1,oq2,oq3)
    }
    A0 = M0; A1 = M1;
  }
#undef MFMA24

  float* pout = part + (size_t)ks * NE_TOT;
  const int rb = row0 + lk * 4;
#pragma unroll
  for (int r = 0; r < 4; ++r) {
    pout[(size_t)(rb + r) * 64 +  0 + lr] = acc0[r];
    pout[(size_t)(rb + r) * 64 + 16 + lr] = acc1[r];
    pout[(size_t)(rb + r) * 64 + 32 + lr] = acc2[r];
    pout[(size_t)(rb + r) * 64 + 48 + lr] = acc3[r];
  }
}

// ---------------------------------------------------------------------------
// Kernel 2: per-row gating -> TRANSPOSED outputs (unchanged — verified)
// ---------------------------------------------------------------------------
template <int KS>
__global__ __launch_bounds__(1024) void gate_rows(const float* __restrict__ part,
                                                  float* __restrict__ gatesT,
                                                  float* __restrict__ tamT) {
  __shared__ float gt[64][65];
  __shared__ float tt[64][65];
  const int tid  = (int)threadIdx.x;
  const int lane = tid & 63;
  const int wid  = tid >> 6;
  const int row0 = (int)blockIdx.x * 64;

#pragma unroll
  for (int r = 0; r < 4; ++r) {
    const int rloc = wid * 4 + r;
    const size_t base = (size_t)(row0 + rloc) * NEXP;

    float logit = 0.f;
#pragma unroll
    for (int s = 0; s < KS; ++s)
      logit += part[(size_t)s * NE_TOT + base + lane];

    float m = logit;
#pragma unroll
    for (int off = 32; off > 0; off >>= 1) m = fmaxf(m, __shfl_xor(m, off));
    float p = expf(logit - m);
    float sum = p;
#pragma unroll
    for (int off = 32; off > 0; off >>= 1) sum += __shfl_xor(sum, off);
    const float gate = p / sum;

    float g = gate;
    int idx = lane;
#pragma unroll
    for (int k = 2; k <= 64; k <<= 1) {
#pragma unroll
      for (int j = k >> 1; j > 0; j >>= 1) {
        float og = __shfl_xor(g, j);
        int   oi = __shfl_xor(idx, j);
        bool iLower     = (lane & j) == 0;
        bool wantFirst  = ((lane & k) == 0) ? iLower : !iLower;
        bool otherFirst = (og > g) || (og == g && oi < idx);
        if (otherFirst == wantFirst) { g = og; idx = oi; }
      }
    }

    float cum = g;
#pragma unroll
    for (int off = 1; off < 64; off <<= 1) {
      float t = __shfl_up(cum, off);
      if (lane >= off) cum += t;
    }
    const bool chosen = (lane == 0) || ((cum - g) < 0.5f);
    const float imp = chosen ? ((float)(NEXP - lane) + g) : 0.f;

    gt[rloc][lane] = gate;
    tt[rloc][idx]  = imp;
  }
  __syncthreads();

#pragma unroll
  for (int p = 0; p < 4; ++p) {
    const int e = p * 16 + wid;
    gatesT[(size_t)e * N_TOK + row0 + lane] = gt[lane][e];
    tamT  [(size_t)e * N_TOK + row0 + lane] = tt[lane][e];
  }
}

// ---------------------------------------------------------------------------
// Kernel 3: per-expert capacity truncation (unchanged — verified)
// ---------------------------------------------------------------------------
__global__ __launch_bounds__(1024) void expert_select(
    const float* __restrict__ gatesT, const float* __restrict__ tamT,
    float* __restrict__ me_sum, int* __restrict__ ce_cnt,
    float* __restrict__ combT) {
  __shared__ int   hist16[16][256];
  __shared__ int   hist[256];
  __shared__ float wsum[16];
  __shared__ int   wice[16];
  __shared__ int   wnnz[16];
  __shared__ int   wcnt[16];
  __shared__ unsigned sh_prefix;
  __shared__ int      sh_k;
  __shared__ int      sh_nnz;

  const int e    = (int)blockIdx.x;
  const int tid  = (int)threadIdx.x;
  const int lane = tid & 63;
  const int wid  = tid >> 6;
  const float* tcol = tamT   + (size_t)e * N_TOK;
  const float* gcol = gatesT + (size_t)e * N_TOK;

  float gsum = 0.f;
  int ccnt = 0, nnzl = 0;
#pragma unroll
  for (int k = 0; k < 4; ++k) {
    int i4 = tid + k * 1024;
    float4 tv = reinterpret_cast<const float4*>(tcol)[i4];
    float4 gv = reinterpret_cast<const float4*>(gcol)[i4];
    gsum += gv.x + gv.y + gv.z + gv.w;
    ccnt += (tv.x > 64.f) + (tv.y > 64.f) + (tv.z > 64.f) + (tv.w > 64.f);
    nnzl += (tv.x != 0.f) + (tv.y != 0.f) + (tv.z != 0.f) + (tv.w != 0.f);
  }
#pragma unroll
  for (int off = 32; off > 0; off >>= 1) {
    gsum += __shfl_xor(gsum, off);
    ccnt += __shfl_xor(ccnt, off);
    nnzl += __shfl_xor(nnzl, off);
  }
  if (lane == 0) { wsum[wid] = gsum; wice[wid] = ccnt; wnnz[wid] = nnzl; }
  __syncthreads();
  if (tid == 0) {
    float t = 0.f; int c = 0, nz = 0;
    for (int w = 0; w < 16; ++w) { t += wsum[w]; c += wice[w]; nz += wnnz[w]; }
    me_sum[e] = t; ce_cnt[e] = c; sh_nnz = nz;
  }
  __syncthreads();
  const int nnz = sh_nnz;

  unsigned vstar = 0u;
  int meq = 0;
  if (nnz > CAP) {
    unsigned prefix = 0;
    int krem = CAP;
    for (int round = 0; round < 4; ++round) {
      const int shift = 24 - 8 * round;
      const unsigned maskAbove =
          (round == 0) ? 0u : (0xFFFFFFFFu << (shift + 8));
      for (int z = tid; z < 16 * 256; z += 1024) ((int*)hist16)[z] = 0;
      __syncthreads();
#pragma unroll
      for (int k = 0; k < 16; ++k) {
        unsigned u = __float_as_uint(tcol[tid + k * 1024]);
        if (u != 0u && (u & maskAbove) == prefix)
          atomicAdd(&hist16[wid][(u >> shift) & 255], 1);
      }
      __syncthreads();
      if (tid < 256) {
        int s = 0;
#pragma unroll
        for (int w = 0; w < 16; ++w) s += hist16[w][tid];
        hist[tid] = s;
      }
      __syncthreads();
      if (wid == 0) {
        int h0 = hist[lane * 4 + 0], h1 = hist[lane * 4 + 1];
        int h2 = hist[lane * 4 + 2], h3 = hist[lane * 4 + 3];
        int lsum = h0 + h1 + h2 + h3;
        int suf = lsum;
#pragma unroll
        for (int off = 1; off < 64; off <<= 1) {
          int t = __shfl_down(suf, off);
          if (lane + off < 64) suf += t;
        }
        int above = suf - lsum;
        int S3 = above + h3, S2 = S3 + h2, S1 = S2 + h1, S0 = S1 + h0;
        if (S0 >= krem && S1    < krem) { sh_prefix = prefix | ((unsigned)(lane*4+0) << shift); sh_k = krem - S1;    }
        if (S1 >= krem && S2    < krem) { sh_prefix = prefix | ((unsigned)(lane*4+1) << shift); sh_k = krem - S2;    }
        if (S2 >= krem && S3    < krem) { sh_prefix = prefix | ((unsigned)(lane*4+2) << shift); sh_k = krem - S3;    }
        if (S3 >= krem && above < krem) { sh_prefix = prefix | ((unsigned)(lane*4+3) << shift); sh_k = krem - above; }
      }
      __syncthreads();
      prefix = sh_prefix;
      krem   = sh_k;
      __syncthreads();
    }
    vstar = prefix;
    meq   = krem;
  }

  float4 tq[4];
#pragma unroll
  for (int q = 0; q < 4; ++q)
    tq[q] = reinterpret_cast<const float4*>(tcol)[tid * 4 + q];
  int cnt = 0;
#pragma unroll
  for (int q = 0; q < 4; ++q) {
    cnt += (__float_as_uint(tq[q].x) == vstar);
    cnt += (__float_as_uint(tq[q].y) == vstar);
    cnt += (__float_as_uint(tq[q].z) == vstar);
    cnt += (__float_as_uint(tq[q].w) == vstar);
  }
  int inc = cnt;
#pragma unroll
  for (int off = 1; off < 64; off <<= 1) {
    int t = __shfl_up(inc, off);
    if (lane >= off) inc += t;
  }
  if (lane == 63) wcnt[wid] = inc;
  __syncthreads();
  if (tid == 0) {
    int run = 0;
    for (int w = 0; w < 16; ++w) { int t = wcnt[w]; wcnt[w] = run; run += t; }
  }
  __syncthreads();
  int exc = (inc - cnt) + wcnt[wid];

  float* ccol = combT + (size_t)e * N_TOK;
#pragma unroll
  for (int q = 0; q < 4; ++q) {
    float4 gq = reinterpret_cast<const float4*>(gcol)[tid * 4 + q];
    float ov[4];
    const float tv[4] = {tq[q].x, tq[q].y, tq[q].z, tq[q].w};
    const float gv[4] = {gq.x, gq.y, gq.z, gq.w};
#pragma unroll
    for (int j = 0; j < 4; ++j) {
      unsigned u = __float_as_uint(tv[j]);
      bool keep;
      if (u == vstar) { keep = (exc < meq); ++exc; }
      else            { keep = (u > vstar); }
      ov[j] = (keep && u != 0u) ? gv[j] : 0.f;
    }
    reinterpret_cast<float4*>(ccol)[tid * 4 + q] =
        make_float4(ov[0], ov[1], ov[2], ov[3]);
  }
}

// ---------------------------------------------------------------------------
// Kernel 4: transpose combT[e][t] -> out[t][e]; block 0 also computes l_aux
// ---------------------------------------------------------------------------
__global__ __launch_bounds__(1024) void transpose_out(
    const float* __restrict__ combT, float* __restrict__ out1,
    const float* __restrict__ me_sum, const int* __restrict__ ce_cnt,
    float* __restrict__ out0) {
  __shared__ float tile[64][65];
  const int tid  = (int)threadIdx.x;
  const int lane = tid & 63;
  const int wid  = tid >> 6;
  const int tok0 = (int)blockIdx.x * 64;
#pragma unroll
  for (int p = 0; p < 4; ++p) {
    const int e = p * 16 + wid;
    tile[lane][e] = combT[(size_t)e * N_TOK + tok0 + lane];
  }
  __syncthreads();
#pragma unroll
  for (int q = 0; q < 4; ++q) {
    const int tok = q * 16 + wid;
    out1[(size_t)(tok0 + tok) * NEXP + lane] = tile[tok][lane];
  }
  if (blockIdx.x == 0 && wid == 0) {
    float v = (me_sum[lane] / (float)N_TOK) *
              ((float)ce_cnt[lane] / (float)N_TOK);
#pragma unroll
    for (int off = 32; off > 0; off >>= 1) v += __shfl_xor(v, off);
    if (lane == 0) out0[0] = v * (float)NEXP;
  }
}

// ---------------------------------------------------------------------------
extern "C" void kernel_launch(void* const* d_in, const int* in_sizes, int n_in,
                              void* d_out, int out_size, void* d_ws, size_t ws_size,
                              hipStream_t stream) {
  const float* x = (const float*)d_in[0];
  const float* W = (const float*)d_in[1];
  float* out = (float*)d_out;
  float* ws  = (float*)d_ws;

  // KS=8 needs (8+2)*4MB scratch; fall back to KS=4 if ws is smaller.
  const bool ks8 = ws_size >= (size_t)(8 + 2) * NE_TOT * 4 + 1024;

  const int KS = ks8 ? 8 : 4;
  float* part   = ws;                       // KS * 4 MB
  float* combT  = ws;                       // aliases part (dead by then)
  float* gatesT = ws + (size_t)KS * NE_TOT; // 4 MB
  float* tamT   = gatesT + NE_TOT;          // 4 MB
  float* me     = tamT + NE_TOT;
  int*   ce     = (int*)(me + 64);

  // W digit arrays (768 KB) live in the gatesT region: written by wdigits,
  // consumed by gemm_mfma, dead before gate_rows overwrites gatesT.
  unsigned short* Wh = (unsigned short*)gatesT;
  unsigned short* Wl = Wh + (size_t)NEXP * KDIM;
  unsigned short* Wq = Wl + (size_t)NEXP * KDIM;

  wdigits<<<(NEXP * KDIM) / 256, 256, 0, stream>>>(W, Wh, Wl, Wq);
  if (ks8) gemm_mfma<8><<<256 * 8, 256, 0, stream>>>(x, Wh, Wl, Wq, part);
  else     gemm_mfma<4><<<256 * 4, 256, 0, stream>>>(x, Wh, Wl, Wq, part);
  if (ks8) gate_rows<8><<<N_TOK / 64, 1024, 0, stream>>>(part, gatesT, tamT);
  else     gate_rows<4><<<N_TOK / 64, 1024, 0, stream>>>(part, gatesT, tamT);
  expert_select<<<NEXP, 1024, 0, stream>>>(gatesT, tamT, me, ce, combT);
  transpose_out<<<N_TOK / 64, 1024, 0, stream>>>(combT, out + 1, me, ce, out);
}

// Round 11
// 73.946 us; speedup vs baseline: 1.1854x; 1.1794x over previous
//
#include <hip/hip_runtime.h>
#include <cstdint>
#include <cstddef>

#define N_TOK  16384
#define NEXP   64
#define KDIM   2048
#define CAP    256   // ceil(16384/64 * 1.0) = 256
#define NE_TOT ((size_t)N_TOK * NEXP)

typedef __attribute__((ext_vector_type(8))) short short8;
typedef __attribute__((ext_vector_type(4))) float f32x4;
typedef __attribute__((ext_vector_type(4))) unsigned int uint4x;

__device__ __forceinline__ unsigned short bf16_rtn(float f) {
  unsigned u = __float_as_uint(f);
  u += 0x7FFFu + ((u >> 16) & 1u);
  return (unsigned short)(u >> 16);
}
__device__ __forceinline__ float bf16_f(unsigned short h) {
  return __uint_as_float((unsigned)h << 16);
}
__device__ __forceinline__ f32x4 MF(short8 a, short8 b, f32x4 c) {
  return __builtin_amdgcn_mfma_f32_16x16x32_bf16(a, b, c, 0, 0, 0);
}
// HW packed f32->bf16 RTNE (bit-identical to bf16_rtn; verified R6->R7)
__device__ __forceinline__ unsigned cvt_pk(float a, float b) {
  unsigned r;
  asm("v_cvt_pk_bf16_f32 %0, %1, %2" : "=v"(r) : "v"(a), "v"(b));
  return r;
}
__device__ __forceinline__ float lo16f(unsigned u) {
  return __uint_as_float(u << 16);
}
__device__ __forceinline__ float hi16f(unsigned u) {
  return __uint_as_float(u & 0xFFFF0000u);
}

// ---------------------------------------------------------------------------
// Kernel 0: split W into 3 bf16 digits, packed [k/8][col][8] (unchanged).
// ---------------------------------------------------------------------------
__global__ __launch_bounds__(256) void wdigits(const float* __restrict__ W,
    unsigned short* __restrict__ Wh, unsigned short* __restrict__ Wl,
    unsigned short* __restrict__ Wq) {
  const int e = (int)blockIdx.x * 256 + (int)threadIdx.x;  // 0..131071
  const int col = e >> 11;
  const int k   = e & 2047;
  const float w = W[(size_t)col * KDIM + k];
  const unsigned short h = bf16_rtn(w);
  const float r1 = w - bf16_f(h);
  const unsigned short lo = bf16_rtn(r1);
  const float r2 = r1 - bf16_f(lo);
  const unsigned short q = bf16_rtn(r2);
  const size_t idx = (size_t)(k >> 3) * 512 + (size_t)col * 8 + (k & 7);
  Wh[idx] = h; Wl[idx] = lo; Wq[idx] = q;
}

// ---------------------------------------------------------------------------
// Kernel 1: logits via 6-term split-bf16 MFMA.
//   R11: revert to measured-best R6 structure, doubled tile: 64 rows/wave
//   (4 row-tiles x 16), 64 cols, KS=8. 96 MFMAs/step amortize 12 B-loads +
//   8 A-loads (ratio 4.8 vs R6 3.7 vs R8-R10 1.7). Grid 512 blocks = 2/CU.
//   Waves of a block share ks -> same B bytes (L1 4-way share).
//   Per-acc MFMA order (hh,hl,lh,ll,qh,hq per step) unchanged since R6 ->
//   logits bit-identical, absmax must repeat 0.0009765625.
// ---------------------------------------------------------------------------
__device__ __forceinline__ void cvt8pk(float4 a, float4 b,
                                       short8& h, short8& lo, short8& q) {
  const float f0 = a.x, f1 = a.y, f2 = a.z, f3 = a.w;
  const float f4 = b.x, f5 = b.y, f6 = b.z, f7 = b.w;
  const unsigned h0 = cvt_pk(f0, f1), h1 = cvt_pk(f2, f3);
  const unsigned h2 = cvt_pk(f4, f5), h3 = cvt_pk(f6, f7);
  const float r0 = f0 - lo16f(h0), r1 = f1 - hi16f(h0);
  const float r2 = f2 - lo16f(h1), r3 = f3 - hi16f(h1);
  const float r4 = f4 - lo16f(h2), r5 = f5 - hi16f(h2);
  const float r6 = f6 - lo16f(h3), r7 = f7 - hi16f(h3);
  const unsigned l0 = cvt_pk(r0, r1), l1 = cvt_pk(r2, r3);
  const unsigned l2 = cvt_pk(r4, r5), l3 = cvt_pk(r6, r7);
  const float s0 = r0 - lo16f(l0), s1 = r1 - hi16f(l0);
  const float s2 = r2 - lo16f(l1), s3 = r3 - hi16f(l1);
  const float s4 = r4 - lo16f(l2), s5 = r5 - hi16f(l2);
  const float s6 = r6 - lo16f(l3), s7 = r7 - hi16f(l3);
  const unsigned q0 = cvt_pk(s0, s1), q1 = cvt_pk(s2, s3);
  const unsigned q2 = cvt_pk(s4, s5), q3 = cvt_pk(s6, s7);
  h  = __builtin_bit_cast(short8, (uint4x){h0, h1, h2, h3});
  lo = __builtin_bit_cast(short8, (uint4x){l0, l1, l2, l3});
  q  = __builtin_bit_cast(short8, (uint4x){q0, q1, q2, q3});
}

template <int KS>
__global__ __launch_bounds__(256) void gemm_mfma(const float* __restrict__ x,
    const unsigned short* __restrict__ Wh, const unsigned short* __restrict__ Wl,
    const unsigned short* __restrict__ Wq, float* __restrict__ part) {
  constexpr int NSTEP = (KDIM / KS) / 32;
  const int tid = (int)threadIdx.x;
  const int l   = tid & 63;
  const int wv  = tid >> 6;
  const int ks  = (int)blockIdx.x % KS;   // waves of a block share ks (B bytes)
  const int mt  = (int)blockIdx.x / KS;   // 64 super-tiles of 256 rows
  const int row0 = mt * 256 + wv * 64;    // this wave's 64 rows
  const int kBeg = ks * (KDIM / KS);
  const int lr = l & 15;
  const int lk = l >> 4;

  f32x4 acc[4][4];                        // [row-tile][col-block]
#pragma unroll
  for (int rt = 0; rt < 4; ++rt)
#pragma unroll
    for (int cb = 0; cb < 4; ++cb) acc[rt][cb] = (f32x4){0.f, 0.f, 0.f, 0.f};

  const float* pa0 = x + (size_t)(row0 + lr) * KDIM + kBeg + lk * 8;
  const size_t bbase = ((size_t)((kBeg >> 3) + lk)) * 64 + lr;
  const short8* BH = (const short8*)Wh + bbase;
  const short8* BL = (const short8*)Wl + bbase;
  const short8* BQ = (const short8*)Wq + bbase;

  // prologue: A for step 0 (4 row-tiles x 2 float4)
  float4 Ac[4][2];
#pragma unroll
  for (int rt = 0; rt < 4; ++rt) {
    const float* p = pa0 + (size_t)rt * 16 * KDIM;
    Ac[rt][0] = *(const float4*)p;
    Ac[rt][1] = *(const float4*)(p + 4);
  }

  for (int s = 0; s < NSTEP; ++s) {
    const int so = s * 256;
    // all 12 B fragments upfront (R6 pattern; L1-shared across the block)
    short8 bh[4], bl[4], bq[4];
#pragma unroll
    for (int cb = 0; cb < 4; ++cb) {
      bh[cb] = BH[so + cb * 16];
      bl[cb] = BL[so + cb * 16];
      bq[cb] = BQ[so + cb * 16];
    }
    // prefetch next step's A
    float4 An[4][2];
    if (s + 1 < NSTEP) {
      const int ko = (s + 1) * 32;
#pragma unroll
      for (int rt = 0; rt < 4; ++rt) {
        const float* p = pa0 + (size_t)rt * 16 * KDIM + ko;
        An[rt][0] = *(const float4*)p;
        An[rt][1] = *(const float4*)(p + 4);
      }
    }
    // convert current A (4 row-tiles) to bf16 digits
    short8 ah[4], al[4], aq[4];
#pragma unroll
    for (int rt = 0; rt < 4; ++rt)
      cvt8pk(Ac[rt][0], Ac[rt][1], ah[rt], al[rt], aq[rt]);

    // 96 MFMAs: per acc the term order is hh,hl,lh,ll,qh,hq (R6-identical)
#pragma unroll
    for (int cb = 0; cb < 4; ++cb) {
#pragma unroll
      for (int rt = 0; rt < 4; ++rt) {
        acc[rt][cb] = MF(ah[rt], bh[cb], acc[rt][cb]);
        acc[rt][cb] = MF(ah[rt], bl[cb], acc[rt][cb]);
        acc[rt][cb] = MF(al[rt], bh[cb], acc[rt][cb]);
        acc[rt][cb] = MF(al[rt], bl[cb], acc[rt][cb]);
        acc[rt][cb] = MF(aq[rt], bh[cb], acc[rt][cb]);
        acc[rt][cb] = MF(ah[rt], bq[cb], acc[rt][cb]);
      }
    }

    if (s + 1 < NSTEP) {
#pragma unroll
      for (int rt = 0; rt < 4; ++rt) { Ac[rt][0] = An[rt][0]; Ac[rt][1] = An[rt][1]; }
    }
  }

  float* pout = part + (size_t)ks * NE_TOT;
#pragma unroll
  for (int rt = 0; rt < 4; ++rt) {
    const int rb = row0 + rt * 16 + lk * 4;
#pragma unroll
    for (int r = 0; r < 4; ++r) {
#pragma unroll
      for (int cb = 0; cb < 4; ++cb)
        pout[(size_t)(rb + r) * 64 + cb * 16 + lr] = acc[rt][cb][r];
    }
  }
}

// ---------------------------------------------------------------------------
// Kernel 2: per-row gating -> TRANSPOSED outputs (unchanged — verified)
// ---------------------------------------------------------------------------
template <int KS>
__global__ __launch_bounds__(1024) void gate_rows(const float* __restrict__ part,
                                                  float* __restrict__ gatesT,
                                                  float* __restrict__ tamT) {
  __shared__ float gt[64][65];
  __shared__ float tt[64][65];
  const int tid  = (int)threadIdx.x;
  const int lane = tid & 63;
  const int wid  = tid >> 6;
  const int row0 = (int)blockIdx.x * 64;

#pragma unroll
  for (int r = 0; r < 4; ++r) {
    const int rloc = wid * 4 + r;
    const size_t base = (size_t)(row0 + rloc) * NEXP;

    float logit = 0.f;
#pragma unroll
    for (int s = 0; s < KS; ++s)
      logit += part[(size_t)s * NE_TOT + base + lane];

    float m = logit;
#pragma unroll
    for (int off = 32; off > 0; off >>= 1) m = fmaxf(m, __shfl_xor(m, off));
    float p = expf(logit - m);
    float sum = p;
#pragma unroll
    for (int off = 32; off > 0; off >>= 1) sum += __shfl_xor(sum, off);
    const float gate = p / sum;

    float g = gate;
    int idx = lane;
#pragma unroll
    for (int k = 2; k <= 64; k <<= 1) {
#pragma unroll
      for (int j = k >> 1; j > 0; j >>= 1) {
        float og = __shfl_xor(g, j);
        int   oi = __shfl_xor(idx, j);
        bool iLower     = (lane & j) == 0;
        bool wantFirst  = ((lane & k) == 0) ? iLower : !iLower;
        bool otherFirst = (og > g) || (og == g && oi < idx);
        if (otherFirst == wantFirst) { g = og; idx = oi; }
      }
    }

    float cum = g;
#pragma unroll
    for (int off = 1; off < 64; off <<= 1) {
      float t = __shfl_up(cum, off);
      if (lane >= off) cum += t;
    }
    const bool chosen = (lane == 0) || ((cum - g) < 0.5f);
    const float imp = chosen ? ((float)(NEXP - lane) + g) : 0.f;

    gt[rloc][lane] = gate;
    tt[rloc][idx]  = imp;
  }
  __syncthreads();

#pragma unroll
  for (int p = 0; p < 4; ++p) {
    const int e = p * 16 + wid;
    gatesT[(size_t)e * N_TOK + row0 + lane] = gt[lane][e];
    tamT  [(size_t)e * N_TOK + row0 + lane] = tt[lane][e];
  }
}

// ---------------------------------------------------------------------------
// Kernel 3: per-expert capacity truncation (unchanged — verified)
// ---------------------------------------------------------------------------
__global__ __launch_bounds__(1024) void expert_select(
    const float* __restrict__ gatesT, const float* __restrict__ tamT,
    float* __restrict__ me_sum, int* __restrict__ ce_cnt,
    float* __restrict__ combT) {
  __shared__ int   hist16[16][256];
  __shared__ int   hist[256];
  __shared__ float wsum[16];
  __shared__ int   wice[16];
  __shared__ int   wnnz[16];
  __shared__ int   wcnt[16];
  __shared__ unsigned sh_prefix;
  __shared__ int      sh_k;
  __shared__ int      sh_nnz;

  const int e    = (int)blockIdx.x;
  const int tid  = (int)threadIdx.x;
  const int lane = tid & 63;
  const int wid  = tid >> 6;
  const float* tcol = tamT   + (size_t)e * N_TOK;
  const float* gcol = gatesT + (size_t)e * N_TOK;

  float gsum = 0.f;
  int ccnt = 0, nnzl = 0;
#pragma unroll
  for (int k = 0; k < 4; ++k) {
    int i4 = tid + k * 1024;
    float4 tv = reinterpret_cast<const float4*>(tcol)[i4];
    float4 gv = reinterpret_cast<const float4*>(gcol)[i4];
    gsum += gv.x + gv.y + gv.z + gv.w;
    ccnt += (tv.x > 64.f) + (tv.y > 64.f) + (tv.z > 64.f) + (tv.w > 64.f);
    nnzl += (tv.x != 0.f) + (tv.y != 0.f) + (tv.z != 0.f) + (tv.w != 0.f);
  }
#pragma unroll
  for (int off = 32; off > 0; off >>= 1) {
    gsum += __shfl_xor(gsum, off);
    ccnt += __shfl_xor(ccnt, off);
    nnzl += __shfl_xor(nnzl, off);
  }
  if (lane == 0) { wsum[wid] = gsum; wice[wid] = ccnt; wnnz[wid] = nnzl; }
  __syncthreads();
  if (tid == 0) {
    float t = 0.f; int c = 0, nz = 0;
    for (int w = 0; w < 16; ++w) { t += wsum[w]; c += wice[w]; nz += wnnz[w]; }
    me_sum[e] = t; ce_cnt[e] = c; sh_nnz = nz;
  }
  __syncthreads();
  const int nnz = sh_nnz;

  unsigned vstar = 0u;
  int meq = 0;
  if (nnz > CAP) {
    unsigned prefix = 0;
    int krem = CAP;
    for (int round = 0; round < 4; ++round) {
      const int shift = 24 - 8 * round;
      const unsigned maskAbove =
          (round == 0) ? 0u : (0xFFFFFFFFu << (shift + 8));
      for (int z = tid; z < 16 * 256; z += 1024) ((int*)hist16)[z] = 0;
      __syncthreads();
#pragma unroll
      for (int k = 0; k < 16; ++k) {
        unsigned u = __float_as_uint(tcol[tid + k * 1024]);
        if (u != 0u && (u & maskAbove) == prefix)
          atomicAdd(&hist16[wid][(u >> shift) & 255], 1);
      }
      __syncthreads();
      if (tid < 256) {
        int s = 0;
#pragma unroll
        for (int w = 0; w < 16; ++w) s += hist16[w][tid];
        hist[tid] = s;
      }
      __syncthreads();
      if (wid == 0) {
        int h0 = hist[lane * 4 + 0], h1 = hist[lane * 4 + 1];
        int h2 = hist[lane * 4 + 2], h3 = hist[lane * 4 + 3];
        int lsum = h0 + h1 + h2 + h3;
        int suf = lsum;
#pragma unroll
        for (int off = 1; off < 64; off <<= 1) {
          int t = __shfl_down(suf, off);
          if (lane + off < 64) suf += t;
        }
        int above = suf - lsum;
        int S3 = above + h3, S2 = S3 + h2, S1 = S2 + h1, S0 = S1 + h0;
        if (S0 >= krem && S1    < krem) { sh_prefix = prefix | ((unsigned)(lane*4+0) << shift); sh_k = krem - S1;    }
        if (S1 >= krem && S2    < krem) { sh_prefix = prefix | ((unsigned)(lane*4+1) << shift); sh_k = krem - S2;    }
        if (S2 >= krem && S3    < krem) { sh_prefix = prefix | ((unsigned)(lane*4+2) << shift); sh_k = krem - S3;    }
        if (S3 >= krem && above < krem) { sh_prefix = prefix | ((unsigned)(lane*4+3) << shift); sh_k = krem - above; }
      }
      __syncthreads();
      prefix = sh_prefix;
      krem   = sh_k;
      __syncthreads();
    }
    vstar = prefix;
    meq   = krem;
  }

  float4 tq[4];
#pragma unroll
  for (int q = 0; q < 4; ++q)
    tq[q] = reinterpret_cast<const float4*>(tcol)[tid * 4 + q];
  int cnt = 0;
#pragma unroll
  for (int q = 0; q < 4; ++q) {
    cnt += (__float_as_uint(tq[q].x) == vstar);
    cnt += (__float_as_uint(tq[q].y) == vstar);
    cnt += (__float_as_uint(tq[q].z) == vstar);
    cnt += (__float_as_uint(tq[q].w) == vstar);
  }
  int inc = cnt;
#pragma unroll
  for (int off = 1; off < 64; off <<= 1) {
    int t = __shfl_up(inc, off);
    if (lane >= off) inc += t;
  }
  if (lane == 63) wcnt[wid] = inc;
  __syncthreads();
  if (tid == 0) {
    int run = 0;
    for (int w = 0; w < 16; ++w) { int t = wcnt[w]; wcnt[w] = run; run += t; }
  }
  __syncthreads();
  int exc = (inc - cnt) + wcnt[wid];

  float* ccol = combT + (size_t)e * N_TOK;
#pragma unroll
  for (int q = 0; q < 4; ++q) {
    float4 gq = reinterpret_cast<const float4*>(gcol)[tid * 4 + q];
    float ov[4];
    const float tv[4] = {tq[q].x, tq[q].y, tq[q].z, tq[q].w};
    const float gv[4] = {gq.x, gq.y, gq.z, gq.w};
#pragma unroll
    for (int j = 0; j < 4; ++j) {
      unsigned u = __float_as_uint(tv[j]);
      bool keep;
      if (u == vstar) { keep = (exc < meq); ++exc; }
      else            { keep = (u > vstar); }
      ov[j] = (keep && u != 0u) ? gv[j] : 0.f;
    }
    reinterpret_cast<float4*>(ccol)[tid * 4 + q] =
        make_float4(ov[0], ov[1], ov[2], ov[3]);
  }
}

// ---------------------------------------------------------------------------
// Kernel 4: transpose combT[e][t] -> out[t][e]; block 0 also computes l_aux
// ---------------------------------------------------------------------------
__global__ __launch_bounds__(1024) void transpose_out(
    const float* __restrict__ combT, float* __restrict__ out1,
    const float* __restrict__ me_sum, const int* __restrict__ ce_cnt,
    float* __restrict__ out0) {
  __shared__ float tile[64][65];
  const int tid  = (int)threadIdx.x;
  const int lane = tid & 63;
  const int wid  = tid >> 6;
  const int tok0 = (int)blockIdx.x * 64;
#pragma unroll
  for (int p = 0; p < 4; ++p) {
    const int e = p * 16 + wid;
    tile[lane][e] = combT[(size_t)e * N_TOK + tok0 + lane];
  }
  __syncthreads();
#pragma unroll
  for (int q = 0; q < 4; ++q) {
    const int tok = q * 16 + wid;
    out1[(size_t)(tok0 + tok) * NEXP + lane] = tile[tok][lane];
  }
  if (blockIdx.x == 0 && wid == 0) {
    float v = (me_sum[lane] / (float)N_TOK) *
              ((float)ce_cnt[lane] / (float)N_TOK);
#pragma unroll
    for (int off = 32; off > 0; off >>= 1) v += __shfl_xor(v, off);
    if (lane == 0) out0[0] = v * (float)NEXP;
  }
}

// ---------------------------------------------------------------------------
extern "C" void kernel_launch(void* const* d_in, const int* in_sizes, int n_in,
                              void* d_out, int out_size, void* d_ws, size_t ws_size,
                              hipStream_t stream) {
  const float* x = (const float*)d_in[0];
  const float* W = (const float*)d_in[1];
  float* out = (float*)d_out;
  float* ws  = (float*)d_ws;

  // KS=8 needs (8+2)*4MB scratch; fall back to KS=4 if ws is smaller.
  const bool ks8 = ws_size >= (size_t)(8 + 2) * NE_TOT * 4 + 1024;

  const int KS = ks8 ? 8 : 4;
  float* part   = ws;                       // KS * 4 MB
  float* combT  = ws;                       // aliases part (dead by then)
  float* gatesT = ws + (size_t)KS * NE_TOT; // 4 MB
  float* tamT   = gatesT + NE_TOT;          // 4 MB
  float* me     = tamT + NE_TOT;
  int*   ce     = (int*)(me + 64);

  // W digit arrays (768 KB) live in the gatesT region: written by wdigits,
  // consumed by gemm_mfma, dead before gate_rows overwrites gatesT.
  unsigned short* Wh = (unsigned short*)gatesT;
  unsigned short* Wl = Wh + (size_t)NEXP * KDIM;
  unsigned short* Wq = Wl + (size_t)NEXP * KDIM;

  wdigits<<<(NEXP * KDIM) / 256, 256, 0, stream>>>(W, Wh, Wl, Wq);
  if (ks8) gemm_mfma<8><<<64 * 8, 256, 0, stream>>>(x, Wh, Wl, Wq, part);
  else     gemm_mfma<4><<<64 * 4, 256, 0, stream>>>(x, Wh, Wl, Wq, part);
  if (ks8) gate_rows<8><<<N_TOK / 64, 1024, 0, stream>>>(part, gatesT, tamT);
  else     gate_rows<4><<<N_TOK / 64, 1024, 0, stream>>>(part, gatesT, tamT);
  expert_select<<<NEXP, 1024, 0, stream>>>(gatesT, tamT, me, ce, combT);
  transpose_out<<<N_TOK / 64, 1024, 0, stream>>>(combT, out + 1, me, ce, out);
}